// Round 3
// baseline (5503.390 us; speedup 1.0000x reference)
//
#include <hip/hip_runtime.h>

// CAGenerator: 64-step neural CA, fp16-MFMA + fused mask/im2col.
// State S[c][n], n = b*1024 + y*32 + x. Per step (4 dispatches):
//   gemm1: P = W1 * im           (M=512, K=736pad, fp16-sw out)
//   gemm2: H = relu(W2 * P)      (M=512, K=512,    fp16-sw out)
//   gemm3: buf1 = W3*H + b3 + state  (M=80/128pad, fp32 out)
//   fuse : live-mask -> buf0 (fp32 state), im (fp16 B-swizzled im2col),
//          pre_next — im2col done as LDS shifted-copies, zero global gathers.
// Swizzled fragment layout (A and B identical):
//   SW[((kc*T + t)*64 + lane)*8 + j] = Mat[t*16+(lane&15)][kc*32+(lane>>4)*8+j]
// mask = uniform()<1.0 is always true in the reference -> no RNG.

#define NPIX 8192
#define T_ALIVE 0.01f

typedef _Float16 f16;
typedef __attribute__((ext_vector_type(8))) _Float16 h8_t;
typedef __attribute__((ext_vector_type(4))) _Float16 h4_t;
typedef __attribute__((ext_vector_type(4))) float f4_t;

#define GLDS16(g, l) __builtin_amdgcn_global_load_lds( \
    (const __attribute__((address_space(1))) void*)(g), \
    (__attribute__((address_space(3))) void*)(l), 16, 0, 0)

// ---------------------------------------------------------------------------
// GEMM: 128x128 block tile, 4 waves (64x64 each), BK=32, double-buffered LDS.
// mode 0: out = fp16 B-sw (bias);  mode 1: same + relu;
// mode 2: out = fp32 buf1[c][n] = acc + bias + addsrc, only c<80.
// ---------------------------------------------------------------------------
__global__ __launch_bounds__(256) void gemm_f16(
    const f16* __restrict__ Asw, const f16* __restrict__ Bsw,
    const float* __restrict__ bias, const float* __restrict__ addsrc,
    void* __restrict__ outp, int Kc, int Mt_tot, int mode)
{
    __shared__ f16 A_lds[2][4096];
    __shared__ f16 B_lds[2][4096];

    const int tid  = threadIdx.x;
    const int lane = tid & 63;
    const int w    = tid >> 6;
    const int wm   = w & 1, wn = w >> 1;
    const int nb   = blockIdx.x, mb = blockIdx.y;

    f4_t acc[4][4];
#pragma unroll
    for (int i = 0; i < 4; ++i)
#pragma unroll
        for (int j = 0; j < 4; ++j) acc[i][j] = f4_t{0.f, 0.f, 0.f, 0.f};

    auto stage = [&](int kc, int d) {
        GLDS16(Asw + (((size_t)kc * Mt_tot + mb * 8 + w    ) * 64 + lane) * 8,
               &A_lds[d][(w    ) * 512]);
        GLDS16(Asw + (((size_t)kc * Mt_tot + mb * 8 + w + 4) * 64 + lane) * 8,
               &A_lds[d][(w + 4) * 512]);
        GLDS16(Bsw + (((size_t)kc * 512    + nb * 8 + w    ) * 64 + lane) * 8,
               &B_lds[d][(w    ) * 512]);
        GLDS16(Bsw + (((size_t)kc * 512    + nb * 8 + w + 4) * 64 + lane) * 8,
               &B_lds[d][(w + 4) * 512]);
    };

    stage(0, 0);
    for (int kc = 0; kc < Kc; ++kc) {
        const int d = kc & 1;
        __syncthreads();
        if (kc + 1 < Kc) stage(kc + 1, d ^ 1);
        h8_t a[4], b[4];
#pragma unroll
        for (int i = 0; i < 4; ++i)
            a[i] = *(const h8_t*)&A_lds[d][((wm * 4 + i) * 64 + lane) * 8];
#pragma unroll
        for (int j = 0; j < 4; ++j)
            b[j] = *(const h8_t*)&B_lds[d][((wn * 4 + j) * 64 + lane) * 8];
#pragma unroll
        for (int i = 0; i < 4; ++i)
#pragma unroll
            for (int j = 0; j < 4; ++j)
                acc[i][j] = __builtin_amdgcn_mfma_f32_16x16x32_f16(
                    a[i], b[j], acc[i][j], 0, 0, 0);
    }

    const int q = lane >> 4, nn = lane & 15;
    if (mode <= 1) {
        f16* out_sw = (f16*)outp;
#pragma unroll
        for (int i = 0; i < 4; ++i) {
            const int m0 = mb * 128 + (wm * 4 + i) * 16 + q * 4;
#pragma unroll
            for (int j = 0; j < 4; ++j) {
                const int nt_g = nb * 8 + wn * 4 + j;
                h4_t v4;
#pragma unroll
                for (int r = 0; r < 4; ++r) {
                    float v = acc[i][j][r] + bias[m0 + r];
                    if (mode == 1) v = fmaxf(v, 0.f);
                    v4[r] = (f16)v;
                }
                f16* dst = out_sw +
                    ((((size_t)(m0 >> 5)) * 512 + nt_g) * 64 +
                     ((m0 >> 3) & 3) * 16 + nn) * 8 + (m0 & 7);
                *(h4_t*)dst = v4;
            }
        }
    } else {
        float* buf1 = (float*)outp;
#pragma unroll
        for (int i = 0; i < 4; ++i) {
            const int m0 = (wm * 4 + i) * 16 + q * 4;
#pragma unroll
            for (int j = 0; j < 4; ++j) {
                const int n = (nb * 8 + wn * 4 + j) * 16 + nn;
#pragma unroll
                for (int r = 0; r < 4; ++r) {
                    const int m = m0 + r;
                    if (m < 80) {
                        const size_t idx = (size_t)m * NPIX + n;
                        buf1[idx] = acc[i][j][r] + bias[m] + addsrc[idx];
                    }
                }
            }
        }
    }
}

// ---------------------------------------------------------------------------
// 3x3 SAME maxpool on channel 0 at flat pixel n (fp32 global).
// ---------------------------------------------------------------------------
__device__ inline float pool3a(const float* __restrict__ a, int n)
{
    const int b = n >> 10, r = n & 1023, y = r >> 5, x = r & 31;
    float mx = -1e30f;
#pragma unroll
    for (int dy = -1; dy <= 1; ++dy) {
        const int yy = y + dy;
        if ((unsigned)yy >= 32u) continue;
#pragma unroll
        for (int dx = -1; dx <= 1; ++dx) {
            const int xx = x + dx;
            if ((unsigned)xx >= 32u) continue;
            mx = fmaxf(mx, a[b * 1024 + yy * 32 + xx]);
        }
    }
    return mx;
}

// ---------------------------------------------------------------------------
// Fused: live-mask + state write + swizzled im2col + next premask.
// Grid (64, 4): blockIdx.x = pixel-block (128 px = 4 rows of one image),
//               blockIdx.y = kc-split (kc range of the im2col output).
// src = unmasked updated state (buf1), or initial state (then pre==null ->
// live ≡ 1 and write_state must be 0).
// ---------------------------------------------------------------------------
__global__ __launch_bounds__(256) void fuse_k(
    const float* __restrict__ src, const float* __restrict__ pre,
    float* __restrict__ state_out, f16* __restrict__ im,
    float* __restrict__ pre_next, int write_state)
{
    __shared__ f16  ms[80][192];    // masked state, rows y0-1..y0+4
    __shared__ float livef[192];
    __shared__ float ch0m[192];     // masked channel 0, fp32 (for pre_next)

    const int pb = blockIdx.x, ks = blockIdx.y;
    const int b  = pb >> 3;
    const int y0 = (pb & 7) * 4;
    const int tid = threadIdx.x;

    // ---- live mask over the 6-row halo window ----
    if (tid < 192) {
        const int row = tid >> 5, x = tid & 31;
        const int y = y0 - 1 + row;
        float lv = 0.f;
        if ((unsigned)y < 32u) {
            const int n = b * 1024 + y * 32 + x;
            bool alive = pool3a(src, n) > T_ALIVE;
            if (pre) alive = alive && (pre[n] > 0.5f);
            lv = alive ? 1.f : 0.f;
        }
        livef[tid] = lv;
    }
    __syncthreads();

    // ---- masked state into LDS (fp16) + fp32 state/ch0 writes ----
    for (int idx = tid; idx < 80 * 192; idx += 256) {
        const int c = idx / 192, p = idx - c * 192;
        const int row = p >> 5, x = p & 31;
        const int y = y0 - 1 + row;
        float v = 0.f;
        if ((unsigned)y < 32u) {
            v = src[(size_t)c * NPIX + b * 1024 + y * 32 + x] * livef[p];
            if (write_state && ks == 0 && row >= 1 && row <= 4)
                state_out[(size_t)c * NPIX + b * 1024 + y * 32 + x] = v;
        }
        ms[c][p] = (f16)v;
        if (c == 0) ch0m[p] = v;
    }
    __syncthreads();

    // ---- next premask from masked fp32 channel 0 ----
    if (ks == 0 && tid < 128) {
        const int lp = tid;                // local pixel
        const int row = (lp >> 5) + 1;     // ms row 1..4
        const int x = lp & 31;
        float mx = -1e30f;
#pragma unroll
        for (int dy = -1; dy <= 1; ++dy)
#pragma unroll
            for (int dx = -1; dx <= 1; ++dx) {
                const int xx = x + dx;
                if ((unsigned)xx < 32u)
                    mx = fmaxf(mx, ch0m[(row + dy) * 32 + xx]);
            }
        pre_next[pb * 128 + lp] = (mx > T_ALIVE) ? 1.f : 0.f;
    }

    // ---- swizzled im2col from LDS (shifted copies) ----
    const int lane = tid & 63, w = tid >> 6;
    const int xloc = lane & 15;
    const int j8   = (lane >> 4) * 8;
    const int kc_lo = ks * 6;
    const int kc_hi = (kc_lo + 6 < 23) ? kc_lo + 6 : 23;
    for (int kc = kc_lo; kc < kc_hi; ++kc) {
        for (int nt = w; nt < 8; nt += 4) {
            const int lp  = nt * 16 + xloc;
            const int row = (lp >> 5) + 1;
            const int x   = lp & 31;
            const int k0  = kc * 32 + j8;
            h8_t v;
#pragma unroll
            for (int jj = 0; jj < 8; ++jj) {
                const int k = k0 + jj;
                f16 val = (f16)0.f;
                if (k < 720) {
                    const int ci = k / 9;
                    const int t9 = k - ci * 9;
                    const int dy = t9 / 3 - 1;
                    const int dx = t9 - (t9 / 3) * 3 - 1;
                    const int xx = x + dx;
                    if ((unsigned)xx < 32u)
                        val = ms[ci][(row + dy) * 32 + xx];
                }
                v[jj] = val;
            }
            *(h8_t*)(im + ((((size_t)kc * 512) + pb * 8 + nt) * 64 + lane) * 8) = v;
        }
    }
}

// Weight swizzle: W (Mreal x Kreal row-major fp32) -> A-fragment-order fp16.
__global__ __launch_bounds__(256) void swz_w(
    const float* __restrict__ W, f16* __restrict__ Asw,
    int Mreal, int Kreal, int Mt_tot, int Kc)
{
    const int idx = blockIdx.x * 256 + threadIdx.x;
    if (idx >= Kc * Mt_tot * 64) return;
    const int lane = idx & 63;
    const int t = idx >> 6;
    const int mt = t % Mt_tot, kc = t / Mt_tot;
    const int m = mt * 16 + (lane & 15);
    const int k0 = kc * 32 + (lane >> 4) * 8;
    h8_t v;
#pragma unroll
    for (int j = 0; j < 8; ++j) {
        const int k = k0 + j;
        const float val = (m < Mreal && k < Kreal) ? W[(size_t)m * Kreal + k] : 0.f;
        v[j] = (f16)val;
    }
    *(h8_t*)(Asw + (size_t)idx * 8) = v;
}

__global__ __launch_bounds__(256) void seed_k(
    const float* __restrict__ z, float* __restrict__ S)
{
    const int idx = blockIdx.x * 256 + threadIdx.x;
    if (idx >= 640) return;
    const int b = idx / 80, c = idx - b * 80;
    const int n = b * 1024 + 16 * 32 + 16;
    S[(size_t)c * NPIX + n] = (c == 0) ? 1.f : z[b * 100 + (c - 1)];
}

extern "C" void kernel_launch(void* const* d_in, const int* in_sizes, int n_in,
                              void* d_out, int out_size, void* d_ws, size_t ws_size,
                              hipStream_t stream)
{
    const float* z  = (const float*)d_in[0];
    const float* W1 = (const float*)d_in[1];   // 512 x 720
    const float* b1 = (const float*)d_in[2];
    const float* W2 = (const float*)d_in[3];   // 512 x 512
    const float* b2 = (const float*)d_in[4];
    const float* W3 = (const float*)d_in[5];   // 80 x 512
    const float* b3 = (const float*)d_in[6];

    char* ws = (char*)d_ws;
    float* buf0 = (float*)ws;                          ws += (size_t)80 * NPIX * 4;
    float* buf1 = (float*)ws;                          ws += (size_t)80 * NPIX * 4;
    float* preA = (float*)ws;                          ws += NPIX * 4;
    float* preB = (float*)ws;                          ws += NPIX * 4;
    f16* A1sw = (f16*)ws;                              ws += (size_t)23 * 32 * 512 * 2;
    f16* A2sw = (f16*)ws;                              ws += (size_t)16 * 32 * 512 * 2;
    f16* A3sw = (f16*)ws;                              ws += (size_t)16 * 8 * 512 * 2;
    f16* im   = (f16*)ws;                              ws += (size_t)23 * 512 * 512 * 2;
    f16* P    = (f16*)ws;                              ws += (size_t)16 * 512 * 512 * 2;
    f16* Hb   = (f16*)ws;                              ws += (size_t)16 * 512 * 512 * 2;

    hipMemsetAsync(buf0, 0, (size_t)80 * NPIX * 4, stream);
    seed_k<<<3, 256, 0, stream>>>(z, buf0);
    swz_w<<<184, 256, 0, stream>>>(W1, A1sw, 512, 720, 32, 23);
    swz_w<<<128, 256, 0, stream>>>(W2, A2sw, 512, 512, 32, 16);
    swz_w<<<32, 256, 0, stream>>>(W3, A3sw, 80, 512, 8, 16);
    // init: im2col + premask of the seeded state (live ≡ 1, no state rewrite)
    fuse_k<<<dim3(64, 4), 256, 0, stream>>>(buf0, nullptr, nullptr, im, preA, 0);

    float* pre_cur = preA;
    float* pre_nxt = preB;
    for (int s = 0; s < 64; ++s) {
        gemm_f16<<<dim3(64, 4), 256, 0, stream>>>(A1sw, im, b1, nullptr, P, 23, 32, 0);
        gemm_f16<<<dim3(64, 4), 256, 0, stream>>>(A2sw, P, b2, nullptr, Hb, 16, 32, 1);
        gemm_f16<<<dim3(64, 1), 256, 0, stream>>>(A3sw, Hb, b3, buf0, buf1, 16, 8, 2);
        fuse_k<<<dim3(64, 4), 256, 0, stream>>>(buf1, pre_cur, buf0, im, pre_nxt, 1);
        float* t = pre_cur; pre_cur = pre_nxt; pre_nxt = t;
    }

    hipMemcpyAsync(d_out, buf0, NPIX * sizeof(float),
                   hipMemcpyDeviceToDevice, stream);
}

// Round 4
// 4679.594 us; speedup vs baseline: 1.1760x; 1.1760x over previous
//
#include <hip/hip_runtime.h>

// CAGenerator: 64-step neural CA — single persistent kernel.
// Key facts: mask=uniform()<1.0 is always true -> no RNG. No ReLU between
// conv3x3 and first 1x1 -> fold Wc = W2@W1 (512x720), bc = W2@b1+b2.
// Per step only 2 GEMMs: H = relu(Wc*im), upd = W3*H + b3.
// 128 WGs (8 images x 16 two-row bands), 1 WG/CU, persistent across all 64
// steps with a manual grid barrier per step. Halo state exchanged via global
// ping-pong buffers U[2] (unmasked updated state) and Ma[2] (masked alpha).
// im2col with K permuted as k = tap*80 + ci: an 8-long k-run = 8 consecutive
// channels at one (dy,dx) tap -> one ds_read_b128 from the masked-state LDS
// tile (channel-contiguous layout). im2col never hits global memory.
// A-fragments (weights) load global->VGPR directly (each used by one wave).

#define NPIX 8192
#define T_ALIVE 0.01f
#define NBLK 128
#define CS 88          // msT channel stride (conflict-friendly, 16B-aligned)

typedef _Float16 f16;
typedef __attribute__((ext_vector_type(8))) _Float16 h8_t;
typedef __attribute__((ext_vector_type(4))) _Float16 h4_t;
typedef __attribute__((ext_vector_type(4))) float f4_t;

// ---------------------------------------------------------------------------
// Prep kernels (run once per launch, ~10-30 us total)
// ---------------------------------------------------------------------------
// Wc[m][k] = sum_h W2[m][h] * W1[h][k]   (m: by + 128j, fp32)
__global__ __launch_bounds__(256) void wc_gemm(
    const float* __restrict__ W1, const float* __restrict__ W2,
    float* __restrict__ Wc)
{
    const int k = blockIdx.x * 256 + threadIdx.x;
    const int by = blockIdx.y;                   // 0..127
    if (k >= 720) return;
    float a0 = 0.f, a1 = 0.f, a2 = 0.f, a3 = 0.f;
    for (int h = 0; h < 512; ++h) {
        const float w1v = W1[h * 720 + k];
        a0 += W2[(by      ) * 512 + h] * w1v;
        a1 += W2[(by + 128) * 512 + h] * w1v;
        a2 += W2[(by + 256) * 512 + h] * w1v;
        a3 += W2[(by + 384) * 512 + h] * w1v;
    }
    Wc[(size_t)(by      ) * 720 + k] = a0;
    Wc[(size_t)(by + 128) * 720 + k] = a1;
    Wc[(size_t)(by + 256) * 720 + k] = a2;
    Wc[(size_t)(by + 384) * 720 + k] = a3;
}

// bc[m] = sum_h W2[m][h]*b1[h] + b2[m]
__global__ __launch_bounds__(256) void bc_k(
    const float* __restrict__ W2, const float* __restrict__ b1,
    const float* __restrict__ b2, float* __restrict__ bc)
{
    const int m = blockIdx.x * 256 + threadIdx.x;
    if (m >= 512) return;
    float a = b2[m];
    for (int h = 0; h < 512; ++h) a += W2[m * 512 + h] * b1[h];
    bc[m] = a;
}

// Wcsw: A-fragment order, K PERMUTED (k_p = tap*80 + ci), zero-pad to 736.
// Wcsw[((kc*32 + mt)*64 + lane)*8 + j] = Wc[mt*16+(lane&15)][orig k], where
// k_p = kc*32 + (lane>>4)*8 + j, orig k = ci*9 + tap.
__global__ __launch_bounds__(256) void swz_wc(
    const float* __restrict__ Wc, f16* __restrict__ Wcsw)
{
    const int idx = blockIdx.x * 256 + threadIdx.x;
    if (idx >= 23 * 32 * 64) return;
    const int lane = idx & 63;
    const int t = idx >> 6;
    const int mt = t & 31, kc = t >> 5;
    const int m = mt * 16 + (lane & 15);
    const int k0 = kc * 32 + (lane >> 4) * 8;
    h8_t v;
#pragma unroll
    for (int j = 0; j < 8; ++j) {
        const int kp = k0 + j;
        float val = 0.f;
        if (kp < 720) {
            const int tap = kp / 80, ci = kp - tap * 80;
            val = Wc[(size_t)m * 720 + ci * 9 + tap];
        }
        v[j] = (f16)val;
    }
    *(h8_t*)(Wcsw + (size_t)idx * 8) = v;
}

// W3sw: plain A-fragment order for W3 (80x512), padded to 128 rows.
__global__ __launch_bounds__(256) void swz_w3(
    const float* __restrict__ W3, f16* __restrict__ W3sw)
{
    const int idx = blockIdx.x * 256 + threadIdx.x;
    if (idx >= 16 * 8 * 64) return;
    const int lane = idx & 63;
    const int t = idx >> 6;
    const int mt = t & 7, kc = t >> 3;
    const int m = mt * 16 + (lane & 15);
    const int k0 = kc * 32 + (lane >> 4) * 8;
    h8_t v;
#pragma unroll
    for (int j = 0; j < 8; ++j)
        v[j] = (f16)((m < 80) ? W3[(size_t)m * 512 + k0 + j] : 0.f);
    *(h8_t*)(W3sw + (size_t)idx * 8) = v;
}

// ---------------------------------------------------------------------------
// Grid barrier (sense via monotonically increasing epoch)
// ---------------------------------------------------------------------------
__device__ inline void gbar(int* cnt, int* flag, int ep)
{
    __syncthreads();   // all WG stores drained (compiler emits vmcnt(0))
    if (threadIdx.x == 0) {
        __threadfence();   // release: L2 writeback, cross-XCD visible
        if (__hip_atomic_fetch_add(cnt, 1, __ATOMIC_ACQ_REL,
                                   __HIP_MEMORY_SCOPE_AGENT) == NBLK - 1) {
            __hip_atomic_store(cnt, 0, __ATOMIC_RELAXED,
                               __HIP_MEMORY_SCOPE_AGENT);
            __hip_atomic_store(flag, ep, __ATOMIC_RELEASE,
                               __HIP_MEMORY_SCOPE_AGENT);
        } else {
            while (__hip_atomic_load(flag, __ATOMIC_ACQUIRE,
                                     __HIP_MEMORY_SCOPE_AGENT) < ep)
                __builtin_amdgcn_s_sleep(2);
        }
        __threadfence();   // acquire: invalidate CU L1 / XCD L2
    }
    __syncthreads();
}

// ---------------------------------------------------------------------------
// Persistent CA kernel. blockIdx.x = b*16 + band; owns rows {2*band, 2*band+1}
// of image b. Halo rows hy=0..3 correspond to y = y0-1 .. y0+2.
// ---------------------------------------------------------------------------
__global__ __launch_bounds__(256, 1) void ca_persist(
    const float* __restrict__ z,   const float* __restrict__ b3g,
    const f16* __restrict__ Wcsw,  const f16* __restrict__ W3sw,
    const float* __restrict__ bc,
    float* __restrict__ U0, float* __restrict__ U1,
    float* __restrict__ Ma0, float* __restrict__ Ma1,
    float* __restrict__ dout, int* __restrict__ bar)
{
    __shared__ f16  msT[128 * CS];      // masked state: [hy*32+x][c], 22.0 KB
    __shared__ f16  Hsw[8 * 4 * 64 * 8];// H chunk, B-frag order, 32 KB
    __shared__ float livef[128];

    const int tid = threadIdx.x;
    const int lane = tid & 63, w = tid >> 6;
    const int q = lane >> 4, li = lane & 15;
    const int blk = blockIdx.x;
    const int b = blk >> 4, band = blk & 15;
    const int y0 = band * 2;
    const int gb = b * 1024;
    int* cnt = bar; int* flag = bar + 1;
    int ep = 0;

    for (int s = 0; s <= 64; ++s) {
        const float* Uprev = (s & 1) ? U0 : U1;
        float*       Ucur  = (s & 1) ? U1 : U0;
        const float* MaPrv = (s & 1) ? Ma0 : Ma1;
        float*       MaCur = (s & 1) ? Ma1 : Ma0;

        // ================= mask phase -> msT (+ Ma / output) ==============
        if (s == 0) {
            if (tid < 128) livef[tid] = 1.f;
            __syncthreads();
            for (int idx = tid; idx < 80 * 128; idx += 256) {
                const int c = idx >> 7, p = idx & 127;
                const int hy = p >> 5, x = p & 31, y = y0 - 1 + hy;
                float v = 0.f;
                if (y == 16 && x == 16) v = c ? z[b * 100 + c - 1] : 1.f;
                msT[p * CS + c] = (f16)v;
                if (c == 0 && hy >= 1 && hy <= 2) MaCur[gb + y * 32 + x] = v;
            }
        } else {
            if (tid < 128) {
                const int hy = tid >> 5, x = tid & 31, y = y0 - 1 + hy;
                float lv = 0.f;
                if ((unsigned)y < 32u) {
                    float post = -1e30f, pre = -1e30f;
                    for (int dy = -1; dy <= 1; ++dy) {
                        const int yy = y + dy;
                        if ((unsigned)yy >= 32u) continue;
                        for (int dx = -1; dx <= 1; ++dx) {
                            const int xx = x + dx;
                            if ((unsigned)xx >= 32u) continue;
                            post = fmaxf(post, Uprev[gb + yy * 32 + xx]);
                            pre  = fmaxf(pre,  MaPrv[gb + yy * 32 + xx]);
                        }
                    }
                    lv = (post > T_ALIVE && pre > T_ALIVE) ? 1.f : 0.f;
                }
                livef[tid] = lv;
            }
            __syncthreads();
            if (s == 64) {   // final: write masked alpha of own rows, done
                if (tid < 128) {
                    const int p = tid, hy = p >> 5, x = p & 31, y = y0 - 1 + hy;
                    if (hy >= 1 && hy <= 2)
                        dout[gb + y * 32 + x] = Uprev[gb + y * 32 + x] * livef[p];
                }
                break;
            }
            for (int idx = tid; idx < 80 * 128; idx += 256) {
                const int c = idx >> 7, p = idx & 127;
                const int hy = p >> 5, x = p & 31, y = y0 - 1 + hy;
                float v = 0.f;
                if ((unsigned)y < 32u)
                    v = Uprev[(size_t)c * NPIX + gb + y * 32 + x] * livef[p];
                msT[p * CS + c] = (f16)v;
                if (c == 0 && hy >= 1 && hy <= 2) MaCur[gb + y * 32 + x] = v;
            }
        }
        __syncthreads();

        // ================= GEMMs: H = relu(Wc*im), upd = W3*H =============
        f4_t acc3[2][4];
#pragma unroll
        for (int i2 = 0; i2 < 2; ++i2)
#pragma unroll
            for (int nt = 0; nt < 4; ++nt)
                acc3[i2][nt] = f4_t{0.f, 0.f, 0.f, 0.f};

        for (int c = 0; c < 2; ++c) {          // M-chunks of 256 H-channels
            // ---- gemm1 chunk: acc1 = Wc[c*256:+256] x im ----
            f4_t acc1[4][4];
#pragma unroll
            for (int i = 0; i < 4; ++i)
#pragma unroll
                for (int nt = 0; nt < 4; ++nt)
                    acc1[i][nt] = f4_t{0.f, 0.f, 0.f, 0.f};

            h8_t aA[4], aB[4];
#pragma unroll
            for (int i = 0; i < 4; ++i)
                aA[i] = *(const h8_t*)(Wcsw +
                    (((size_t)(0 * 32 + c * 16 + w * 4 + i)) * 64 + lane) * 8);

            for (int kc = 0; kc < 23; ++kc) {
                h8_t* acur = (kc & 1) ? aB : aA;
                h8_t* anxt = (kc & 1) ? aA : aB;
                if (kc < 22) {
#pragma unroll
                    for (int i = 0; i < 4; ++i)
                        anxt[i] = *(const h8_t*)(Wcsw +
                            ((((size_t)(kc + 1) * 32 + c * 16 + w * 4 + i)) * 64
                             + lane) * 8);
                }
                // B fragments straight from msT (permuted-K im2col)
                const int k0 = kc * 32 + q * 8;
                const int tap = k0 / 80;
                const int ci0 = k0 - tap * 80;
                const int dy = tap / 3 - 1;
                const int dx = tap - (tap / 3) * 3 - 1;
                const bool kvalid = (k0 < 720);
                h8_t bf[4];
#pragma unroll
                for (int nt = 0; nt < 4; ++nt) {
                    const int nloc = nt * 16 + li;
                    const int row = 1 + (nloc >> 5);
                    const int xx = (nloc & 31) + dx;
                    h8_t f;
#pragma unroll
                    for (int j = 0; j < 8; ++j) f[j] = (f16)0.f;
                    if (kvalid && (unsigned)xx < 32u)
                        f = *(const h8_t*)&msT[((row + dy) * 32 + xx) * CS + ci0];
                    bf[nt] = f;
                }
#pragma unroll
                for (int i = 0; i < 4; ++i)
#pragma unroll
                    for (int nt = 0; nt < 4; ++nt)
                        acc1[i][nt] = __builtin_amdgcn_mfma_f32_16x16x32_f16(
                            acur[i], bf[nt], acc1[i][nt], 0, 0, 0);
            }
            __syncthreads();   // prior gemm3 done reading Hsw (chunk 1)

            // ---- Hsw write: relu(acc1 + bc), B-frag order (local kc2) ----
#pragma unroll
            for (int i = 0; i < 4; ++i) {
                const int mloc = (w * 4 + i) * 16 + q * 4;
#pragma unroll
                for (int nt = 0; nt < 4; ++nt) {
                    h4_t v4;
#pragma unroll
                    for (int r = 0; r < 4; ++r) {
                        float v = acc1[i][nt][r] + bc[c * 256 + mloc + r];
                        v4[r] = (f16)fmaxf(v, 0.f);
                    }
                    const int dst = ((((mloc >> 5) * 4 + nt) * 64 +
                                     ((mloc >> 3) & 3) * 16 + li)) * 8 + (mloc & 7);
                    *(h4_t*)&Hsw[dst] = v4;
                }
            }
            __syncthreads();

            // ---- gemm3 partial-K over this chunk ----
            for (int kc2 = 0; kc2 < 8; ++kc2) {
                const h8_t a0 = *(const h8_t*)(W3sw +
                    (((size_t)(c * 8 + kc2) * 8 + (w * 2 + 0)) * 64 + lane) * 8);
                const h8_t a1 = *(const h8_t*)(W3sw +
                    (((size_t)(c * 8 + kc2) * 8 + (w * 2 + 1)) * 64 + lane) * 8);
#pragma unroll
                for (int nt = 0; nt < 4; ++nt) {
                    const h8_t bfh = *(const h8_t*)&Hsw[((kc2 * 4 + nt) * 64 + lane) * 8];
                    acc3[0][nt] = __builtin_amdgcn_mfma_f32_16x16x32_f16(
                        a0, bfh, acc3[0][nt], 0, 0, 0);
                    acc3[1][nt] = __builtin_amdgcn_mfma_f32_16x16x32_f16(
                        a1, bfh, acc3[1][nt], 0, 0, 0);
                }
            }
            __syncthreads();
        }

        // ================= epilogue: U_cur = M_s + upd + b3 ===============
#pragma unroll
        for (int i2 = 0; i2 < 2; ++i2) {
            const int m0 = (w * 2 + i2) * 16 + q * 4;
#pragma unroll
            for (int nt = 0; nt < 4; ++nt) {
                const int nloc = nt * 16 + li;
                const int hy = 1 + (nloc >> 5);
                const int x = nloc & 31;
                const int y = y0 + (nloc >> 5);
                const float lv = livef[hy * 32 + x];
#pragma unroll
                for (int r = 0; r < 4; ++r) {
                    const int m = m0 + r;
                    if (m < 80) {
                        float base;
                        if (s == 0)
                            base = (y == 16 && x == 16)
                                   ? (m ? z[b * 100 + m - 1] : 1.f) : 0.f;
                        else
                            base = Uprev[(size_t)m * NPIX + gb + y * 32 + x] * lv;
                        Ucur[(size_t)m * NPIX + gb + y * 32 + x] =
                            base + acc3[i2][nt][r] + b3g[m];
                    }
                }
            }
        }

        // ================= grid barrier ===================================
        ++ep;
        gbar(cnt, flag, ep);
    }
}

// ---------------------------------------------------------------------------
extern "C" void kernel_launch(void* const* d_in, const int* in_sizes, int n_in,
                              void* d_out, int out_size, void* d_ws, size_t ws_size,
                              hipStream_t stream)
{
    const float* z  = (const float*)d_in[0];
    const float* W1 = (const float*)d_in[1];   // 512 x 720
    const float* b1 = (const float*)d_in[2];
    const float* W2 = (const float*)d_in[3];   // 512 x 512
    const float* b2 = (const float*)d_in[4];
    const float* W3 = (const float*)d_in[5];   // 80 x 512
    const float* b3 = (const float*)d_in[6];

    char* ws = (char*)d_ws;
    float* U0   = (float*)ws;  ws += (size_t)80 * NPIX * 4;
    float* U1   = (float*)ws;  ws += (size_t)80 * NPIX * 4;
    float* Ma0  = (float*)ws;  ws += NPIX * 4;
    float* Ma1  = (float*)ws;  ws += NPIX * 4;
    float* bc   = (float*)ws;  ws += 512 * 4;
    float* Wc   = (float*)ws;  ws += (size_t)512 * 720 * 4;
    f16*   Wcsw = (f16*)ws;    ws += (size_t)23 * 32 * 64 * 8 * 2;
    f16*   W3sw = (f16*)ws;    ws += (size_t)16 * 8 * 64 * 8 * 2;
    int*   bar  = (int*)ws;    ws += 16;
    // total ~7.7 MB

    hipMemsetAsync(bar, 0, 8, stream);
    wc_gemm<<<dim3(3, 128), 256, 0, stream>>>(W1, W2, Wc);
    bc_k<<<2, 256, 0, stream>>>(W2, b1, b2, bc);
    swz_wc<<<184, 256, 0, stream>>>(Wc, Wcsw);
    swz_w3<<<32, 256, 0, stream>>>(W3, W3sw);

    ca_persist<<<NBLK, 256, 0, stream>>>(z, b3, Wcsw, W3sw, bc,
                                         U0, U1, Ma0, Ma1,
                                         (float*)d_out, bar);
}